// Round 2
// baseline (682.900 us; speedup 1.0000x reference)
//
#include <hip/hip_runtime.h>
#include <math.h>

#define NB 16
#define NC 256
#define NN 4096
#define NHD 8
#define HD 32
#define BHD 128   // NB*NHD
#define KSPLIT 4

typedef unsigned short bf16_t;

__device__ __forceinline__ float bf2f(unsigned int u16) {
  return __uint_as_float(u16 << 16);
}
__device__ __forceinline__ bf16_t f2bf(float f) {
  unsigned int u = __float_as_uint(f);
  return (bf16_t)((u + 0x7FFFu + ((u >> 16) & 1u)) >> 16);
}
// expand uint4 (8 packed bf16) -> 8 floats
__device__ __forceinline__ void bf8_expand(uint4 u, float* f) {
  f[0] = bf2f(u.x & 0xffffu); f[1] = bf2f(u.x >> 16);
  f[2] = bf2f(u.y & 0xffffu); f[3] = bf2f(u.y >> 16);
  f[4] = bf2f(u.z & 0xffffu); f[5] = bf2f(u.z >> 16);
  f[6] = bf2f(u.w & 0xffffu); f[7] = bf2f(u.w >> 16);
}

__device__ __forceinline__ float softplusf(float x) {
  return fmaxf(x, 0.0f) + log1pf(expf(-fabsf(x)));
}

// ---------------------------------------------------------------------------
// Kernel 1: qkv projection.  qkv[b,n,j] = sum_k x[b,k,n]*W[j,k] + bias[j]
// fp32 compute, bf16 store. Tile BM=128 x BN=128 x BK=16, 256 thr, 8x8 micro.
// ---------------------------------------------------------------------------
__global__ __launch_bounds__(256) void k_qkv(
    const float* __restrict__ x, const float* __restrict__ Wq,
    const float* __restrict__ bq, const float* __restrict__ Wkv,
    const float* __restrict__ bkv, bf16_t* __restrict__ qkv)
{
  __shared__ float As[16][128];
  __shared__ float Bs[16][132];
  const int tid = threadIdx.x;
  const int m0 = blockIdx.x * 128;
  const int j0 = blockIdx.y * 128;
  const int b  = blockIdx.z;
  const int lm4 = (tid & 15) * 4;   // m sub-offset
  const int jn4 = (tid >> 4) * 4;   // j sub-offset
  const float* xb = x + (size_t)b * NC * NN;
  float acc[8][8];
#pragma unroll
  for (int i = 0; i < 8; ++i)
#pragma unroll
    for (int j = 0; j < 8; ++j) acc[i][j] = 0.f;

  for (int k0 = 0; k0 < NC; k0 += 16) {
#pragma unroll
    for (int r = 0; r < 2; ++r) {
      int idx = r * 256 + tid;          // 0..511
      int k  = idx >> 5;                // 0..15
      int ms = (idx & 31) * 4;          // 0..124
      *(float4*)&As[k][ms] = *(const float4*)(xb + (size_t)(k0 + k) * NN + m0 + ms);
    }
#pragma unroll
    for (int r = 0; r < 2; ++r) {
      int idx = r * 256 + tid;          // 0..511
      int j   = idx >> 2;               // 0..127
      int k4  = (idx & 3) * 4;          // 0,4,8,12
      int jg  = j0 + j;
      const float* wr = (jg < NC) ? (Wq + (size_t)jg * NC)
                                  : (Wkv + (size_t)(jg - NC) * NC);
      float4 wv = *(const float4*)(wr + k0 + k4);
      Bs[k4 + 0][j] = wv.x; Bs[k4 + 1][j] = wv.y;
      Bs[k4 + 2][j] = wv.z; Bs[k4 + 3][j] = wv.w;
    }
    __syncthreads();
#pragma unroll
    for (int kk = 0; kk < 16; ++kk) {
      float a[8], bb[8];
      *(float4*)&a[0]  = *(const float4*)&As[kk][lm4];
      *(float4*)&a[4]  = *(const float4*)&As[kk][64 + lm4];
      *(float4*)&bb[0] = *(const float4*)&Bs[kk][jn4];
      *(float4*)&bb[4] = *(const float4*)&Bs[kk][64 + jn4];
#pragma unroll
      for (int i = 0; i < 8; ++i)
#pragma unroll
        for (int j = 0; j < 8; ++j)
          acc[i][j] += a[i] * bb[j];
    }
    __syncthreads();
  }

  float bias[8];
#pragma unroll
  for (int jh = 0; jh < 2; ++jh)
#pragma unroll
    for (int jj = 0; jj < 4; ++jj) {
      int jc = j0 + jh * 64 + jn4 + jj;
      bias[jh * 4 + jj] = (jc < NC) ? bq[jc] : bkv[jc - NC];
    }
#pragma unroll
  for (int ih = 0; ih < 2; ++ih)
#pragma unroll
    for (int i = 0; i < 4; ++i) {
      int m = m0 + ih * 64 + lm4 + i;
      bf16_t* orow = qkv + ((size_t)b * NN + m) * 768 + j0;
#pragma unroll
      for (int jh = 0; jh < 2; ++jh) {
        ushort4 o;
        o.x = f2bf(acc[ih * 4 + i][jh * 4 + 0] + bias[jh * 4 + 0]);
        o.y = f2bf(acc[ih * 4 + i][jh * 4 + 1] + bias[jh * 4 + 1]);
        o.z = f2bf(acc[ih * 4 + i][jh * 4 + 2] + bias[jh * 4 + 2]);
        o.w = f2bf(acc[ih * 4 + i][jh * 4 + 3] + bias[jh * 4 + 3]);
        *(ushort4*)(orow + jh * 64 + jn4) = o;
      }
    }
}

// ---------------------------------------------------------------------------
// Kernel 2: focusing feature map, in place on q and k (bf16 in/out).
// One wave per token; lane handles 4 channels.
// ---------------------------------------------------------------------------
__global__ __launch_bounds__(256) void k_focus(
    bf16_t* __restrict__ qkv, const float* __restrict__ scale_param)
{
  const int lane = threadIdx.x & 63;
  const int w = threadIdx.x >> 6;
  const size_t t = (size_t)blockIdx.x * 4 + w;
  bf16_t* row = qkv + t * 768;
  ushort4 qu = *(ushort4*)(row + lane * 4);
  ushort4 ku = *(ushort4*)(row + 256 + lane * 4);
  float4 s4 = *(const float4*)(scale_param + lane * 4);
  float q[4] = {bf2f(qu.x), bf2f(qu.y), bf2f(qu.z), bf2f(qu.w)};
  float k[4] = {bf2f(ku.x), bf2f(ku.y), bf2f(ku.z), bf2f(ku.w)};
  float s[4] = {s4.x, s4.y, s4.z, s4.w};
  float q3[4], k3[4];
  float sq2 = 0.f, sq6 = 0.f, sk2 = 0.f, sk6 = 0.f;
#pragma unroll
  for (int i = 0; i < 4; ++i) {
    float sc = softplusf(s[i]);
    float qi = (fmaxf(q[i], 0.f) + 1e-6f) / sc;
    float ki = (fmaxf(k[i], 0.f) + 1e-6f) / sc;
    float qc = qi * qi * qi;
    float kc = ki * ki * ki;
    sq2 += qi * qi;  sk2 += ki * ki;
    sq6 += qc * qc;  sk6 += kc * kc;
    q3[i] = qc; k3[i] = kc;
  }
#pragma unroll
  for (int off = 32; off > 0; off >>= 1) {
    sq2 += __shfl_xor(sq2, off);
    sq6 += __shfl_xor(sq6, off);
    sk2 += __shfl_xor(sk2, off);
    sk6 += __shfl_xor(sk6, off);
  }
  float qs = sqrtf(sq2) * rsqrtf(sq6);   // q_norm / q3_norm
  float ks = sqrtf(sk2) * rsqrtf(sk6);
  ushort4 qo, ko;
  qo.x = f2bf(q3[0] * qs); qo.y = f2bf(q3[1] * qs);
  qo.z = f2bf(q3[2] * qs); qo.w = f2bf(q3[3] * qs);
  ko.x = f2bf(k3[0] * ks); ko.y = f2bf(k3[1] * ks);
  ko.z = f2bf(k3[2] * ks); ko.w = f2bf(k3[3] * ks);
  *(ushort4*)(row + lane * 4) = qo;
  *(ushort4*)(row + 256 + lane * 4) = ko;
}

// ---------------------------------------------------------------------------
// Kernel 3: per-head kv_state (32x32) and k-sum, split-K over tokens.
// ---------------------------------------------------------------------------
__global__ __launch_bounds__(256) void k_kvstate(
    const bf16_t* __restrict__ qkv, float* __restrict__ kvsp,
    float* __restrict__ ksump)
{
  const int bh = blockIdx.x;
  const int spl = blockIdx.y;
  const int b = bh >> 3, h = bh & 7;
  __shared__ float ks[64][36];
  __shared__ float vs[64][36];
  const int tid = threadIdx.x;
  const int c = tid >> 3;
  const int d4 = (tid & 7) * 4;
  float acc0 = 0.f, acc1 = 0.f, acc2 = 0.f, acc3 = 0.f, ksacc = 0.f;
  const int t0base = spl * (NN / KSPLIT);
  for (int t0 = t0base; t0 < t0base + NN / KSPLIT; t0 += 64) {
#pragma unroll
    for (int r = 0; r < 2; ++r) {
      int idx = r * 256 + tid;          // 0..511
      int tok = idx >> 3;               // 0..63
      int slot = idx & 7;               // 0..7 (0-3: k, 4-7: v), 8 ch each
      const bf16_t* rowp = qkv + ((size_t)b * NN + t0 + tok) * 768 + 256 + h * HD;
      uint4 u;
      float f[8];
      if (slot < 4) {
        u = *(const uint4*)(rowp + slot * 8);
        bf8_expand(u, f);
#pragma unroll
        for (int e = 0; e < 8; ++e) ks[tok][slot * 8 + e] = f[e];
      } else {
        u = *(const uint4*)(rowp + 256 + (slot - 4) * 8);
        bf8_expand(u, f);
#pragma unroll
        for (int e = 0; e < 8; ++e) vs[tok][(slot - 4) * 8 + e] = f[e];
      }
    }
    __syncthreads();
#pragma unroll 4
    for (int t = 0; t < 64; ++t) {
      float kc = ks[t][c];
      float vv[4];
      *(float4*)vv = *(const float4*)&vs[t][d4];
      acc0 += kc * vv[0]; acc1 += kc * vv[1];
      acc2 += kc * vv[2]; acc3 += kc * vv[3];
      ksacc += kc;
    }
    __syncthreads();
  }
  float o[4] = {acc0, acc1, acc2, acc3};
  *(float4*)(kvsp + ((size_t)spl * BHD + bh) * (HD * HD) + c * HD + d4) = *(float4*)o;
  if (d4 == 0) ksump[((size_t)spl * BHD + bh) * HD + c] = ksacc;
}

// ---------------------------------------------------------------------------
// Kernel 4: combine split-K partials.
// ---------------------------------------------------------------------------
__global__ __launch_bounds__(256) void k_combine(
    const float* __restrict__ kvsp, const float* __restrict__ ksump,
    float* __restrict__ kvs, float* __restrict__ ksum)
{
  int i = blockIdx.x * 256 + threadIdx.x;   // < 131072
  float v = 0.f;
#pragma unroll
  for (int s = 0; s < KSPLIT; ++s) v += kvsp[(size_t)s * BHD * HD * HD + i];
  kvs[i] = v;
  if (i < BHD * HD) {
    float u = 0.f;
#pragma unroll
    for (int s = 0; s < KSPLIT; ++s) u += ksump[(size_t)s * BHD * HD + i];
    ksum[i] = u;
  }
}

// ---------------------------------------------------------------------------
// Kernel 5: attn = (q @ kv_state)*z + depthwise5x5(v) + dwc_b   (bf16 out)
// block: 8x8 spatial tile for one (b,h). 256 thr: d = tid&31, 8 token-groups.
// ---------------------------------------------------------------------------
__global__ __launch_bounds__(256) void k_attnout(
    const bf16_t* __restrict__ qkv, const float* __restrict__ kvs,
    const float* __restrict__ ksum, const float* __restrict__ dwc_w,
    const float* __restrict__ dwc_b, bf16_t* __restrict__ attn)
{
  const int bh = blockIdx.z;
  const int b = bh >> 3, h = bh & 7;
  const int y0 = blockIdx.y * 8, x0 = blockIdx.x * 8;
  __shared__ float qt[64][36];
  __shared__ float vt[32][145];
  __shared__ float zt[64];
  const int tid = threadIdx.x;

  // q tile: 64 tokens x 32 ch (uint4 = 8 ch per load, 256 loads total)
  {
    int tok = tid >> 2, slot = tid & 3;
    int ty = tok >> 3, tx = tok & 7;
    int n = (y0 + ty) * 64 + (x0 + tx);
    uint4 u = *(const uint4*)(qkv + ((size_t)b * NN + n) * 768 + h * HD + slot * 8);
    float f[8];
    bf8_expand(u, f);
#pragma unroll
    for (int e = 0; e < 8; ++e) qt[tok][slot * 8 + e] = f[e];
  }
  // v tile with +-2 halo: 12x12 spatial, d-major in LDS (576 uint4 loads)
  for (int idx = tid; idx < 576; idx += 256) {
    int ht = idx >> 2, slot = idx & 3;
    int hy = y0 + (ht / 12) - 2;
    int hx = x0 + (ht % 12) - 2;
    float f[8] = {0.f, 0.f, 0.f, 0.f, 0.f, 0.f, 0.f, 0.f};
    if (hy >= 0 && hy < 64 && hx >= 0 && hx < 64) {
      int n = hy * 64 + hx;
      uint4 u = *(const uint4*)(qkv + ((size_t)b * NN + n) * 768 + 512 + h * HD + slot * 8);
      bf8_expand(u, f);
    }
#pragma unroll
    for (int e = 0; e < 8; ++e) vt[slot * 8 + e][ht] = f[e];
  }
  __syncthreads();

  if (tid < 64) {
    float dot = 0.f;
#pragma unroll
    for (int c = 0; c < HD; ++c)
      dot += qt[tid][c] * ksum[(size_t)bh * HD + c];
    zt[tid] = 1.f / (dot + 1e-6f);
  }
  __syncthreads();

  const int d = tid & 31;
  const int tg = tid >> 5;
  float kvc[32];
#pragma unroll
  for (int c = 0; c < 32; ++c)
    kvc[c] = kvs[(size_t)bh * (HD * HD) + c * HD + d];
  float wr[25];
#pragma unroll
  for (int j = 0; j < 25; ++j) wr[j] = dwc_w[d * 25 + j];
  const float bd = dwc_b[d];

#pragma unroll
  for (int tt = 0; tt < 8; ++tt) {
    int t = tg * 8 + tt;
    int ty = t >> 3, tx = t & 7;
    float mv = 0.f;
#pragma unroll
    for (int c = 0; c < 32; ++c) mv += qt[t][c] * kvc[c];
    float acc = mv * zt[t] + bd;
#pragma unroll
    for (int ky = 0; ky < 5; ++ky)
#pragma unroll
      for (int kx = 0; kx < 5; ++kx)
        acc += vt[d][(ty + ky) * 12 + (tx + kx)] * wr[ky * 5 + kx];
    int n = (y0 + ty) * 64 + (x0 + tx);
    attn[((size_t)b * NN + n) * NC + h * HD + d] = f2bf(acc);
  }
}

// ---------------------------------------------------------------------------
// Kernel 6: output projection + transpose store (fp32 out).
// out[b,j,n] = sum_k attn[b,n,k]*Wp[j,k] + bp[j]
// ---------------------------------------------------------------------------
__global__ __launch_bounds__(256) void k_proj(
    const bf16_t* __restrict__ attn, const float* __restrict__ Wp,
    const float* __restrict__ bp, float* __restrict__ out)
{
  __shared__ float As[16][132];
  __shared__ float Bs[16][132];
  const int tid = threadIdx.x;
  const int m0 = blockIdx.x * 128;
  const int j0 = blockIdx.y * 128;
  const int b = blockIdx.z;
  const int lm4 = (tid & 15) * 4;
  const int jn4 = (tid >> 4) * 4;
  float acc[8][8];
#pragma unroll
  for (int i = 0; i < 8; ++i)
#pragma unroll
    for (int j = 0; j < 8; ++j) acc[i][j] = 0.f;

  for (int k0 = 0; k0 < NC; k0 += 16) {
    {
      int m = tid >> 1;                // 0..127
      int slot = tid & 1;              // k8 = slot*8
      uint4 u = *(const uint4*)(attn + ((size_t)b * NN + m0 + m) * NC + k0 + slot * 8);
      float f[8];
      bf8_expand(u, f);
#pragma unroll
      for (int e = 0; e < 8; ++e) As[slot * 8 + e][m] = f[e];
    }
#pragma unroll
    for (int r = 0; r < 2; ++r) {
      int idx = r * 256 + tid;
      int j = idx >> 2;
      int k4 = (idx & 3) * 4;
      float4 wv = *(const float4*)(Wp + (size_t)(j0 + j) * NC + k0 + k4);
      Bs[k4 + 0][j] = wv.x; Bs[k4 + 1][j] = wv.y;
      Bs[k4 + 2][j] = wv.z; Bs[k4 + 3][j] = wv.w;
    }
    __syncthreads();
#pragma unroll
    for (int kk = 0; kk < 16; ++kk) {
      float a[8], bb[8];
      *(float4*)&a[0]  = *(const float4*)&As[kk][lm4];
      *(float4*)&a[4]  = *(const float4*)&As[kk][64 + lm4];
      *(float4*)&bb[0] = *(const float4*)&Bs[kk][jn4];
      *(float4*)&bb[4] = *(const float4*)&Bs[kk][64 + jn4];
#pragma unroll
      for (int i = 0; i < 8; ++i)
#pragma unroll
        for (int j = 0; j < 8; ++j)
          acc[i][j] += a[i] * bb[j];
    }
    __syncthreads();
  }

  // store transposed: coalesced along n
#pragma unroll
  for (int jh = 0; jh < 2; ++jh)
#pragma unroll
    for (int jj = 0; jj < 4; ++jj) {
      int j = j0 + jh * 64 + jn4 + jj;
      float bv = bp[j];
      float* orow = out + (size_t)b * NC * NN + (size_t)j * NN + m0;
#pragma unroll
      for (int ih = 0; ih < 2; ++ih) {
        float4 o;
        o.x = acc[ih * 4 + 0][jh * 4 + jj] + bv;
        o.y = acc[ih * 4 + 1][jh * 4 + jj] + bv;
        o.z = acc[ih * 4 + 2][jh * 4 + jj] + bv;
        o.w = acc[ih * 4 + 3][jh * 4 + jj] + bv;
        *(float4*)(orow + ih * 64 + lm4) = o;
      }
    }
}

// ---------------------------------------------------------------------------
extern "C" void kernel_launch(void* const* d_in, const int* in_sizes, int n_in,
                              void* d_out, int out_size, void* d_ws, size_t ws_size,
                              hipStream_t stream)
{
  (void)in_sizes; (void)n_in; (void)out_size; (void)ws_size;
  const float* x    = (const float*)d_in[0];
  const float* Wq   = (const float*)d_in[1];
  const float* bq   = (const float*)d_in[2];
  const float* Wkv  = (const float*)d_in[3];
  const float* bkv  = (const float*)d_in[4];
  const float* Wp   = (const float*)d_in[5];
  const float* bp   = (const float*)d_in[6];
  const float* dwcw = (const float*)d_in[7];
  const float* dwcb = (const float*)d_in[8];
  const float* sp   = (const float*)d_in[9];
  float* out = (float*)d_out;

  // workspace layout (bytes):
  //   qkv  : 65536*768*2  = 100663296   (bf16)
  //   attn : 65536*256*2  =  33554432   (bf16)
  //   kvsp : 4*128*1024*4 =   2097152   (fp32)
  //   ksump: 4*128*32*4   =     65536
  //   kvs  : 128*1024*4   =    524288
  //   ksum : 128*32*4     =     16384
  // total ~137 MB
  char* wsb = (char*)d_ws;
  bf16_t* qkv  = (bf16_t*)wsb;
  bf16_t* attn = (bf16_t*)(wsb + 100663296u);
  float*  kvsp = (float*)(wsb + 100663296u + 33554432u);
  float*  ksump= kvsp + (size_t)KSPLIT * BHD * HD * HD;
  float*  kvs  = ksump + (size_t)KSPLIT * BHD * HD;
  float*  ksum = kvs + (size_t)BHD * HD * HD;

  k_qkv<<<dim3(32, 6, 16), 256, 0, stream>>>(x, Wq, bq, Wkv, bkv, qkv);
  k_focus<<<16384, 256, 0, stream>>>(qkv, sp);
  k_kvstate<<<dim3(BHD, KSPLIT), 256, 0, stream>>>(qkv, kvsp, ksump);
  k_combine<<<512, 256, 0, stream>>>(kvsp, ksump, kvs, ksum);
  k_attnout<<<dim3(8, 8, BHD), 256, 0, stream>>>(qkv, kvs, ksum, dwcw, dwcb, attn);
  k_proj<<<dim3(32, 2, 16), 256, 0, stream>>>(attn, Wp, bp, out);
}

// Round 3
// 387.643 us; speedup vs baseline: 1.7617x; 1.7617x over previous
//
#include <hip/hip_runtime.h>
#include <math.h>

#define NB 16
#define NC 256
#define NN 4096
#define HD 32
#define BHD 128   // NB*NHD
#define KSPLIT 4

typedef unsigned short bf16_t;
typedef __attribute__((ext_vector_type(4))) float floatx4;
typedef __attribute__((ext_vector_type(8))) short shortx8;

__device__ __forceinline__ float bf2f(unsigned int u16) {
  return __uint_as_float(u16 << 16);
}
__device__ __forceinline__ bf16_t f2bf(float f) {
  unsigned int u = __float_as_uint(f);
  return (bf16_t)((u + 0x7FFFu + ((u >> 16) & 1u)) >> 16);
}
__device__ __forceinline__ void bf8_expand(uint4 u, float* f) {
  f[0] = bf2f(u.x & 0xffffu); f[1] = bf2f(u.x >> 16);
  f[2] = bf2f(u.y & 0xffffu); f[3] = bf2f(u.y >> 16);
  f[4] = bf2f(u.z & 0xffffu); f[5] = bf2f(u.z >> 16);
  f[6] = bf2f(u.w & 0xffffu); f[7] = bf2f(u.w >> 16);
}
__device__ __forceinline__ float softplusf(float x) {
  return fmaxf(x, 0.0f) + log1pf(expf(-fabsf(x)));
}

// async global->LDS, 16B per lane; lds base must be wave-uniform
__device__ __forceinline__ void gl_lds16(const void* g, void* l) {
  __builtin_amdgcn_global_load_lds(
      (const __attribute__((address_space(1))) unsigned int*)g,
      (__attribute__((address_space(3))) unsigned int*)l, 16, 0, 0);
}

// ---------------------------------------------------------------------------
// prep: x [b][c][n] fp32 -> xbf [b][n][c] bf16 (transpose + cast)
// grid (64 n-tiles, 4 c-tiles, 16 b), 256 thr
// ---------------------------------------------------------------------------
__global__ __launch_bounds__(256) void k_prepx(
    const float* __restrict__ x, bf16_t* __restrict__ xbf)
{
  __shared__ float T[64][68];
  const int tid = threadIdx.x;
  const int n0 = blockIdx.x * 64, c0 = blockIdx.y * 64, b = blockIdx.z;
  const float* xb = x + (size_t)b * NC * NN;
#pragma unroll
  for (int it = 0; it < 4; ++it) {
    int c = it * 16 + (tid >> 4);
    int n4 = (tid & 15) * 4;
    float4 v = *(const float4*)(xb + (size_t)(c0 + c) * NN + n0 + n4);
    T[c][n4 + 0] = v.x; T[c][n4 + 1] = v.y;
    T[c][n4 + 2] = v.z; T[c][n4 + 3] = v.w;
  }
  __syncthreads();
  bf16_t* ob = xbf + (size_t)b * NN * NC;
#pragma unroll
  for (int it = 0; it < 2; ++it) {
    int n = it * 32 + (tid >> 3);
    int ch = (tid & 7) * 8;
    unsigned short e[8];
#pragma unroll
    for (int j = 0; j < 8; ++j) e[j] = f2bf(T[ch + j][n]);
    uint4 u;
    u.x = e[0] | ((unsigned)e[1] << 16); u.y = e[2] | ((unsigned)e[3] << 16);
    u.z = e[4] | ((unsigned)e[5] << 16); u.w = e[6] | ((unsigned)e[7] << 16);
    *(uint4*)(ob + (size_t)(n0 + n) * NC + c0 + ch) = u;
  }
}

// ---------------------------------------------------------------------------
// prep: pack Wq+Wkv -> Wqkvb bf16 [768][256]; Wp -> Wpb bf16; bq+bkv -> bias768
// ---------------------------------------------------------------------------
__global__ __launch_bounds__(256) void k_prepw(
    const float* __restrict__ Wq, const float* __restrict__ Wkv,
    const float* __restrict__ Wp, const float* __restrict__ bq,
    const float* __restrict__ bkv, bf16_t* __restrict__ Wqkvb,
    bf16_t* __restrict__ Wpb, float* __restrict__ bias768)
{
  const int blk = blockIdx.x;
  const int tid = threadIdx.x;
  if (blk < 768) {
    const float* src = (blk < 256) ? (Wq + (size_t)blk * NC)
                                   : (Wkv + (size_t)(blk - 256) * NC);
    Wqkvb[(size_t)blk * NC + tid] = f2bf(src[tid]);
  } else if (blk < 1024) {
    int j = blk - 768;
    Wpb[(size_t)j * NC + tid] = f2bf(Wp[(size_t)j * NC + tid]);
  } else {
    for (int i = tid; i < 768; i += 256)
      bias768[i] = (i < 256) ? bq[i] : bkv[i - 256];
  }
}

// ---------------------------------------------------------------------------
// Kernel 1: qkv projection via bf16 MFMA.
// qkv[b,m,j] = sum_k xbf[b,m,k]*Wqkvb[j,k] + bias768[j]
// 128x128 tile, BK=32, 4 waves each 64x64 (4x4 of 16x16x32). bf16 out.
// ---------------------------------------------------------------------------
__global__ __launch_bounds__(256) void k_qkv_mfma(
    const bf16_t* __restrict__ xbf, const bf16_t* __restrict__ Wqkvb,
    const float* __restrict__ bias768, bf16_t* __restrict__ qkv)
{
  __shared__ bf16_t As[128 * 32];
  __shared__ bf16_t Bs[128 * 32];
  const int tid = threadIdx.x;
  const int lane = tid & 63;
  const int w = tid >> 6;
  const int b = blockIdx.z;
  const int m0 = blockIdx.x * 128;
  const int n0 = blockIdx.y * 128;
  const bf16_t* Ab = xbf + ((size_t)b * NN + m0) * NC;
  const bf16_t* Bb = Wqkvb + (size_t)n0 * NC;

  const int wm = (w & 1) * 64;
  const int wn = (w >> 1) * 64;
  const int srow = w * 32 + (lane >> 2);    // staging row (+r*16)
  const int scol = (lane & 3) * 8;          // staging k-offset (elements)
  const int fm = lane & 15;                 // fragment m/n
  const int kg = lane >> 4;                 // fragment k-group

  floatx4 acc[4][4];
#pragma unroll
  for (int i = 0; i < 4; ++i)
#pragma unroll
    for (int j = 0; j < 4; ++j) {
      floatx4 z = {0.f, 0.f, 0.f, 0.f};
      acc[i][j] = z;
    }

  for (int k0 = 0; k0 < NC; k0 += 32) {
#pragma unroll
    for (int r = 0; r < 2; ++r) {
      gl_lds16(Ab + (size_t)(srow + r * 16) * NC + k0 + scol,
               &As[(w * 32 + r * 16) * 32]);
      gl_lds16(Bb + (size_t)(srow + r * 16) * NC + k0 + scol,
               &Bs[(w * 32 + r * 16) * 32]);
    }
    __syncthreads();
    shortx8 af[4], bfg[4];
#pragma unroll
    for (int t = 0; t < 4; ++t) {
      af[t]  = *(const shortx8*)&As[(wm + t * 16 + fm) * 32 + kg * 8];
      bfg[t] = *(const shortx8*)&Bs[(wn + t * 16 + fm) * 32 + kg * 8];
    }
#pragma unroll
    for (int tm = 0; tm < 4; ++tm)
#pragma unroll
      for (int tn = 0; tn < 4; ++tn)
        acc[tm][tn] = __builtin_amdgcn_mfma_f32_16x16x32_bf16(
            af[tm], bfg[tn], acc[tm][tn], 0, 0, 0);
    __syncthreads();
  }

  float bv[4];
#pragma unroll
  for (int tn = 0; tn < 4; ++tn)
    bv[tn] = bias768[n0 + wn + tn * 16 + fm];

  bf16_t* obase = qkv + ((size_t)b * NN + m0) * 768;
#pragma unroll
  for (int tm = 0; tm < 4; ++tm) {
    int mrow = wm + tm * 16 + kg * 4;
#pragma unroll
    for (int tn = 0; tn < 4; ++tn) {
      int n = n0 + wn + tn * 16 + fm;
#pragma unroll
      for (int r = 0; r < 4; ++r)
        obase[(size_t)(mrow + r) * 768 + n] = f2bf(acc[tm][tn][r] + bv[tn]);
    }
  }
}

// ---------------------------------------------------------------------------
// Kernel 2: focusing feature map, in place on q and k (bf16).
// ---------------------------------------------------------------------------
__global__ __launch_bounds__(256) void k_focus(
    bf16_t* __restrict__ qkv, const float* __restrict__ scale_param)
{
  const int lane = threadIdx.x & 63;
  const int w = threadIdx.x >> 6;
  const size_t t = (size_t)blockIdx.x * 4 + w;
  bf16_t* row = qkv + t * 768;
  ushort4 qu = *(ushort4*)(row + lane * 4);
  ushort4 ku = *(ushort4*)(row + 256 + lane * 4);
  float4 s4 = *(const float4*)(scale_param + lane * 4);
  float q[4] = {bf2f(qu.x), bf2f(qu.y), bf2f(qu.z), bf2f(qu.w)};
  float k[4] = {bf2f(ku.x), bf2f(ku.y), bf2f(ku.z), bf2f(ku.w)};
  float s[4] = {s4.x, s4.y, s4.z, s4.w};
  float q3[4], k3[4];
  float sq2 = 0.f, sq6 = 0.f, sk2 = 0.f, sk6 = 0.f;
#pragma unroll
  for (int i = 0; i < 4; ++i) {
    float sc = softplusf(s[i]);
    float qi = (fmaxf(q[i], 0.f) + 1e-6f) / sc;
    float ki = (fmaxf(k[i], 0.f) + 1e-6f) / sc;
    float qc = qi * qi * qi;
    float kc = ki * ki * ki;
    sq2 += qi * qi;  sk2 += ki * ki;
    sq6 += qc * qc;  sk6 += kc * kc;
    q3[i] = qc; k3[i] = kc;
  }
#pragma unroll
  for (int off = 32; off > 0; off >>= 1) {
    sq2 += __shfl_xor(sq2, off);
    sq6 += __shfl_xor(sq6, off);
    sk2 += __shfl_xor(sk2, off);
    sk6 += __shfl_xor(sk6, off);
  }
  float qs = sqrtf(sq2) * rsqrtf(sq6);
  float ks = sqrtf(sk2) * rsqrtf(sk6);
  ushort4 qo, ko;
  qo.x = f2bf(q3[0] * qs); qo.y = f2bf(q3[1] * qs);
  qo.z = f2bf(q3[2] * qs); qo.w = f2bf(q3[3] * qs);
  ko.x = f2bf(k3[0] * ks); ko.y = f2bf(k3[1] * ks);
  ko.z = f2bf(k3[2] * ks); ko.w = f2bf(k3[3] * ks);
  *(ushort4*)(row + lane * 4) = qo;
  *(ushort4*)(row + 256 + lane * 4) = ko;
}

// ---------------------------------------------------------------------------
// Kernel 3: per-head kv_state (32x32) and k-sum, split-K over tokens.
// ---------------------------------------------------------------------------
__global__ __launch_bounds__(256) void k_kvstate(
    const bf16_t* __restrict__ qkv, float* __restrict__ kvsp,
    float* __restrict__ ksump)
{
  const int bh = blockIdx.x;
  const int spl = blockIdx.y;
  const int b = bh >> 3, h = bh & 7;
  __shared__ float ks[64][36];
  __shared__ float vs[64][36];
  const int tid = threadIdx.x;
  const int c = tid >> 3;
  const int d4 = (tid & 7) * 4;
  float acc0 = 0.f, acc1 = 0.f, acc2 = 0.f, acc3 = 0.f, ksacc = 0.f;
  const int t0base = spl * (NN / KSPLIT);
  for (int t0 = t0base; t0 < t0base + NN / KSPLIT; t0 += 64) {
#pragma unroll
    for (int r = 0; r < 2; ++r) {
      int idx = r * 256 + tid;
      int tok = idx >> 3;
      int slot = idx & 7;
      const bf16_t* rowp = qkv + ((size_t)b * NN + t0 + tok) * 768 + 256 + h * HD;
      uint4 u;
      float f[8];
      if (slot < 4) {
        u = *(const uint4*)(rowp + slot * 8);
        bf8_expand(u, f);
#pragma unroll
        for (int e = 0; e < 8; ++e) ks[tok][slot * 8 + e] = f[e];
      } else {
        u = *(const uint4*)(rowp + 256 + (slot - 4) * 8);
        bf8_expand(u, f);
#pragma unroll
        for (int e = 0; e < 8; ++e) vs[tok][(slot - 4) * 8 + e] = f[e];
      }
    }
    __syncthreads();
#pragma unroll 4
    for (int t = 0; t < 64; ++t) {
      float kc = ks[t][c];
      float vv[4];
      *(float4*)vv = *(const float4*)&vs[t][d4];
      acc0 += kc * vv[0]; acc1 += kc * vv[1];
      acc2 += kc * vv[2]; acc3 += kc * vv[3];
      ksacc += kc;
    }
    __syncthreads();
  }
  float o[4] = {acc0, acc1, acc2, acc3};
  *(float4*)(kvsp + ((size_t)spl * BHD + bh) * (HD * HD) + c * HD + d4) = *(float4*)o;
  if (d4 == 0) ksump[((size_t)spl * BHD + bh) * HD + c] = ksacc;
}

// ---------------------------------------------------------------------------
// Kernel 4: combine split-K partials.
// ---------------------------------------------------------------------------
__global__ __launch_bounds__(256) void k_combine(
    const float* __restrict__ kvsp, const float* __restrict__ ksump,
    float* __restrict__ kvs, float* __restrict__ ksum)
{
  int i = blockIdx.x * 256 + threadIdx.x;
  float v = 0.f;
#pragma unroll
  for (int s = 0; s < KSPLIT; ++s) v += kvsp[(size_t)s * BHD * HD * HD + i];
  kvs[i] = v;
  if (i < BHD * HD) {
    float u = 0.f;
#pragma unroll
    for (int s = 0; s < KSPLIT; ++s) u += ksump[(size_t)s * BHD * HD + i];
    ksum[i] = u;
  }
}

// ---------------------------------------------------------------------------
// Kernel 5: attn = (q @ kv_state)*z + depthwise5x5(v) + dwc_b  (bf16 out)
// ---------------------------------------------------------------------------
__global__ __launch_bounds__(256) void k_attnout(
    const bf16_t* __restrict__ qkv, const float* __restrict__ kvs,
    const float* __restrict__ ksum, const float* __restrict__ dwc_w,
    const float* __restrict__ dwc_b, bf16_t* __restrict__ attn)
{
  const int bh = blockIdx.z;
  const int b = bh >> 3, h = bh & 7;
  const int y0 = blockIdx.y * 8, x0 = blockIdx.x * 8;
  __shared__ float qt[64][36];
  __shared__ float vt[32][145];
  __shared__ float zt[64];
  const int tid = threadIdx.x;

  {
    int tok = tid >> 2, slot = tid & 3;
    int ty = tok >> 3, tx = tok & 7;
    int n = (y0 + ty) * 64 + (x0 + tx);
    uint4 u = *(const uint4*)(qkv + ((size_t)b * NN + n) * 768 + h * HD + slot * 8);
    float f[8];
    bf8_expand(u, f);
#pragma unroll
    for (int e = 0; e < 8; ++e) qt[tok][slot * 8 + e] = f[e];
  }
  for (int idx = tid; idx < 576; idx += 256) {
    int ht = idx >> 2, slot = idx & 3;
    int hy = y0 + (ht / 12) - 2;
    int hx = x0 + (ht % 12) - 2;
    float f[8] = {0.f, 0.f, 0.f, 0.f, 0.f, 0.f, 0.f, 0.f};
    if (hy >= 0 && hy < 64 && hx >= 0 && hx < 64) {
      int n = hy * 64 + hx;
      uint4 u = *(const uint4*)(qkv + ((size_t)b * NN + n) * 768 + 512 + h * HD + slot * 8);
      bf8_expand(u, f);
    }
#pragma unroll
    for (int e = 0; e < 8; ++e) vt[slot * 8 + e][ht] = f[e];
  }
  __syncthreads();

  if (tid < 64) {
    float dot = 0.f;
#pragma unroll
    for (int c = 0; c < HD; ++c)
      dot += qt[tid][c] * ksum[(size_t)bh * HD + c];
    zt[tid] = 1.f / (dot + 1e-6f);
  }
  __syncthreads();

  const int d = tid & 31;
  const int tg = tid >> 5;
  float kvc[32];
#pragma unroll
  for (int c = 0; c < 32; ++c)
    kvc[c] = kvs[(size_t)bh * (HD * HD) + c * HD + d];
  float wr[25];
#pragma unroll
  for (int j = 0; j < 25; ++j) wr[j] = dwc_w[d * 25 + j];
  const float bd = dwc_b[d];

#pragma unroll
  for (int tt = 0; tt < 8; ++tt) {
    int t = tg * 8 + tt;
    int ty = t >> 3, tx = t & 7;
    float mv = 0.f;
#pragma unroll
    for (int c = 0; c < 32; ++c) mv += qt[t][c] * kvc[c];
    float acc = mv * zt[t] + bd;
#pragma unroll
    for (int ky = 0; ky < 5; ++ky)
#pragma unroll
      for (int kx = 0; kx < 5; ++kx)
        acc += vt[d][(ty + ky) * 12 + (tx + kx)] * wr[ky * 5 + kx];
    int n = (y0 + ty) * 64 + (x0 + tx);
    attn[((size_t)b * NN + n) * NC + h * HD + d] = f2bf(acc);
  }
}

// ---------------------------------------------------------------------------
// Kernel 6: output projection via bf16 MFMA, fp32 transposed store.
// out[b,j,t] = sum_k attn[b,t,k]*Wpb[j,k] + bp[j]
// ---------------------------------------------------------------------------
__global__ __launch_bounds__(256) void k_proj_mfma(
    const bf16_t* __restrict__ attn, const bf16_t* __restrict__ Wpb,
    const float* __restrict__ bp, float* __restrict__ out)
{
  __shared__ bf16_t As[128 * 32];
  __shared__ bf16_t Bs[128 * 32];
  const int tid = threadIdx.x;
  const int lane = tid & 63;
  const int w = tid >> 6;
  const size_t m0 = (size_t)blockIdx.x * 128;   // global row in [0, 65536)
  const int n0 = blockIdx.y * 128;
  const bf16_t* Ab = attn + m0 * NC;
  const bf16_t* Bb = Wpb + (size_t)n0 * NC;

  const int wm = (w & 1) * 64;
  const int wn = (w >> 1) * 64;
  const int srow = w * 32 + (lane >> 2);
  const int scol = (lane & 3) * 8;
  const int fm = lane & 15;
  const int kg = lane >> 4;

  floatx4 acc[4][4];
#pragma unroll
  for (int i = 0; i < 4; ++i)
#pragma unroll
    for (int j = 0; j < 4; ++j) {
      floatx4 z = {0.f, 0.f, 0.f, 0.f};
      acc[i][j] = z;
    }

  for (int k0 = 0; k0 < NC; k0 += 32) {
#pragma unroll
    for (int r = 0; r < 2; ++r) {
      gl_lds16(Ab + (size_t)(srow + r * 16) * NC + k0 + scol,
               &As[(w * 32 + r * 16) * 32]);
      gl_lds16(Bb + (size_t)(srow + r * 16) * NC + k0 + scol,
               &Bs[(w * 32 + r * 16) * 32]);
    }
    __syncthreads();
    shortx8 af[4], bfg[4];
#pragma unroll
    for (int t = 0; t < 4; ++t) {
      af[t]  = *(const shortx8*)&As[(wm + t * 16 + fm) * 32 + kg * 8];
      bfg[t] = *(const shortx8*)&Bs[(wn + t * 16 + fm) * 32 + kg * 8];
    }
#pragma unroll
    for (int tm = 0; tm < 4; ++tm)
#pragma unroll
      for (int tn = 0; tn < 4; ++tn)
        acc[tm][tn] = __builtin_amdgcn_mfma_f32_16x16x32_bf16(
            af[tm], bfg[tn], acc[tm][tn], 0, 0, 0);
    __syncthreads();
  }

  const int b = (int)(m0 >> 12);
  const int t0 = (int)(m0 & 4095);
  float* ob = out + (size_t)b * NC * NN;
#pragma unroll
  for (int tn = 0; tn < 4; ++tn) {
    int j = n0 + wn + tn * 16 + fm;
    float bj = bp[j];
#pragma unroll
    for (int tm = 0; tm < 4; ++tm) {
      int trow = t0 + wm + tm * 16 + kg * 4;
      float4 o;
      o.x = acc[tm][tn][0] + bj;
      o.y = acc[tm][tn][1] + bj;
      o.z = acc[tm][tn][2] + bj;
      o.w = acc[tm][tn][3] + bj;
      *(float4*)(ob + (size_t)j * NN + trow) = o;
    }
  }
}

// ---------------------------------------------------------------------------
extern "C" void kernel_launch(void* const* d_in, const int* in_sizes, int n_in,
                              void* d_out, int out_size, void* d_ws, size_t ws_size,
                              hipStream_t stream)
{
  (void)in_sizes; (void)n_in; (void)out_size; (void)ws_size;
  const float* x    = (const float*)d_in[0];
  const float* Wq   = (const float*)d_in[1];
  const float* bq   = (const float*)d_in[2];
  const float* Wkv  = (const float*)d_in[3];
  const float* bkv  = (const float*)d_in[4];
  const float* Wp   = (const float*)d_in[5];
  const float* bp   = (const float*)d_in[6];
  const float* dwcw = (const float*)d_in[7];
  const float* dwcb = (const float*)d_in[8];
  const float* sp   = (const float*)d_in[9];
  float* out = (float*)d_out;

  // workspace layout (~137.7 MB):
  //   qkv   bf16 100,663,296 B
  //   attn  bf16  33,554,432 B   (aliased as xbf: disjoint lifetimes)
  //   kvsp/ksump/kvs/ksum fp32 ~2.7 MB
  //   Wqkvb/Wpb bf16 + bias768 fp32 ~0.5 MB
  char* wsb = (char*)d_ws;
  bf16_t* qkv  = (bf16_t*)wsb;
  bf16_t* attn = (bf16_t*)(wsb + 100663296u);
  bf16_t* xbf  = attn;                                   // alias (xbf dead before attn written)
  float*  kvsp = (float*)(wsb + 100663296u + 33554432u);
  float*  ksump = kvsp + (size_t)KSPLIT * BHD * HD * HD;
  float*  kvs   = ksump + (size_t)KSPLIT * BHD * HD;
  float*  ksum  = kvs + (size_t)BHD * HD * HD;
  bf16_t* Wqkvb = (bf16_t*)(ksum + BHD * HD);
  bf16_t* Wpb   = Wqkvb + 768 * 256;
  float*  bias768 = (float*)(Wpb + 256 * 256);

  k_prepx<<<dim3(64, 4, 16), 256, 0, stream>>>(x, xbf);
  k_prepw<<<1025, 256, 0, stream>>>(Wq, Wkv, Wp, bq, bkv, Wqkvb, Wpb, bias768);
  k_qkv_mfma<<<dim3(32, 6, 16), 256, 0, stream>>>(xbf, Wqkvb, bias768, qkv);
  k_focus<<<16384, 256, 0, stream>>>(qkv, sp);
  k_kvstate<<<dim3(BHD, KSPLIT), 256, 0, stream>>>(qkv, kvsp, ksump);
  k_combine<<<512, 256, 0, stream>>>(kvsp, ksump, kvs, ksum);
  k_attnout<<<dim3(8, 8, BHD), 256, 0, stream>>>(qkv, kvs, ksum, dwcw, dwcb, attn);
  k_proj_mfma<<<dim3(512, 2), 256, 0, stream>>>(attn, Wpb, bp, out);
}

// Round 4
// 337.462 us; speedup vs baseline: 2.0236x; 1.1487x over previous
//
#include <hip/hip_runtime.h>
#include <math.h>

#define NB 16
#define NC 256
#define NN 4096
#define HD 32
#define BHD 128   // NB*NHD
#define KSPLIT 4

typedef unsigned short bf16_t;
typedef __attribute__((ext_vector_type(4))) float floatx4;
typedef __attribute__((ext_vector_type(8))) short shortx8;

__device__ __forceinline__ float bf2f(unsigned int u16) {
  return __uint_as_float(u16 << 16);
}
__device__ __forceinline__ bf16_t f2bf(float f) {
  unsigned int u = __float_as_uint(f);
  return (bf16_t)((u + 0x7FFFu + ((u >> 16) & 1u)) >> 16);
}
__device__ __forceinline__ void bf8_expand(uint4 u, float* f) {
  f[0] = bf2f(u.x & 0xffffu); f[1] = bf2f(u.x >> 16);
  f[2] = bf2f(u.y & 0xffffu); f[3] = bf2f(u.y >> 16);
  f[4] = bf2f(u.z & 0xffffu); f[5] = bf2f(u.z >> 16);
  f[6] = bf2f(u.w & 0xffffu); f[7] = bf2f(u.w >> 16);
}
__device__ __forceinline__ float softplusf(float x) {
  return fmaxf(x, 0.0f) + log1pf(expf(-fabsf(x)));
}

// async global->LDS, 16B per lane; lds base must be wave-uniform
__device__ __forceinline__ void gl_lds16(const void* g, void* l) {
  __builtin_amdgcn_global_load_lds(
      (const __attribute__((address_space(1))) unsigned int*)g,
      (__attribute__((address_space(3))) unsigned int*)l, 16, 0, 0);
}

// ---------------------------------------------------------------------------
// prep: x [b][c][n] fp32 -> xbf [b][n][c] bf16 (transpose + cast)
// ---------------------------------------------------------------------------
__global__ __launch_bounds__(256) void k_prepx(
    const float* __restrict__ x, bf16_t* __restrict__ xbf)
{
  __shared__ float T[64][68];
  const int tid = threadIdx.x;
  const int n0 = blockIdx.x * 64, c0 = blockIdx.y * 64, b = blockIdx.z;
  const float* xb = x + (size_t)b * NC * NN;
#pragma unroll
  for (int it = 0; it < 4; ++it) {
    int c = it * 16 + (tid >> 4);
    int n4 = (tid & 15) * 4;
    float4 v = *(const float4*)(xb + (size_t)(c0 + c) * NN + n0 + n4);
    T[c][n4 + 0] = v.x; T[c][n4 + 1] = v.y;
    T[c][n4 + 2] = v.z; T[c][n4 + 3] = v.w;
  }
  __syncthreads();
  bf16_t* ob = xbf + (size_t)b * NN * NC;
#pragma unroll
  for (int it = 0; it < 2; ++it) {
    int n = it * 32 + (tid >> 3);
    int ch = (tid & 7) * 8;
    unsigned short e[8];
#pragma unroll
    for (int j = 0; j < 8; ++j) e[j] = f2bf(T[ch + j][n]);
    uint4 u;
    u.x = e[0] | ((unsigned)e[1] << 16); u.y = e[2] | ((unsigned)e[3] << 16);
    u.z = e[4] | ((unsigned)e[5] << 16); u.w = e[6] | ((unsigned)e[7] << 16);
    *(uint4*)(ob + (size_t)(n0 + n) * NC + c0 + ch) = u;
  }
}

// ---------------------------------------------------------------------------
// prep: pack weights to bf16, biases, and rscale[c] = 1/softplus(scale[c])
// ---------------------------------------------------------------------------
__global__ __launch_bounds__(256) void k_prepw(
    const float* __restrict__ Wq, const float* __restrict__ Wkv,
    const float* __restrict__ Wp, const float* __restrict__ bq,
    const float* __restrict__ bkv, const float* __restrict__ sp,
    bf16_t* __restrict__ Wqkvb, bf16_t* __restrict__ Wpb,
    float* __restrict__ bias768, float* __restrict__ rscale)
{
  const int blk = blockIdx.x;
  const int tid = threadIdx.x;
  if (blk < 768) {
    const float* src = (blk < 256) ? (Wq + (size_t)blk * NC)
                                   : (Wkv + (size_t)(blk - 256) * NC);
    Wqkvb[(size_t)blk * NC + tid] = f2bf(src[tid]);
  } else if (blk < 1024) {
    int j = blk - 768;
    Wpb[(size_t)j * NC + tid] = f2bf(Wp[(size_t)j * NC + tid]);
  } else if (blk == 1024) {
    for (int i = tid; i < 768; i += 256)
      bias768[i] = (i < 256) ? bq[i] : bkv[i - 256];
  } else {
    rscale[tid] = 1.0f / softplusf(sp[tid]);
  }
}

// ---------------------------------------------------------------------------
// Kernel 1: qkv projection via bf16 MFMA.
// 128x128 tile, BK=32, 4 waves each 64x64 (4x4 of 16x16x32). bf16 out.
// ---------------------------------------------------------------------------
__global__ __launch_bounds__(256) void k_qkv_mfma(
    const bf16_t* __restrict__ xbf, const bf16_t* __restrict__ Wqkvb,
    const float* __restrict__ bias768, bf16_t* __restrict__ qkv)
{
  __shared__ bf16_t As[128 * 32];
  __shared__ bf16_t Bs[128 * 32];
  const int tid = threadIdx.x;
  const int lane = tid & 63;
  const int w = tid >> 6;
  const int b = blockIdx.z;
  const int m0 = blockIdx.x * 128;
  const int n0 = blockIdx.y * 128;
  const bf16_t* Ab = xbf + ((size_t)b * NN + m0) * NC;
  const bf16_t* Bb = Wqkvb + (size_t)n0 * NC;

  const int wm = (w & 1) * 64;
  const int wn = (w >> 1) * 64;
  const int srow = w * 32 + (lane >> 2);
  const int scol = (lane & 3) * 8;
  const int fm = lane & 15;
  const int kg = lane >> 4;

  floatx4 acc[4][4];
#pragma unroll
  for (int i = 0; i < 4; ++i)
#pragma unroll
    for (int j = 0; j < 4; ++j) {
      floatx4 z = {0.f, 0.f, 0.f, 0.f};
      acc[i][j] = z;
    }

  for (int k0 = 0; k0 < NC; k0 += 32) {
#pragma unroll
    for (int r = 0; r < 2; ++r) {
      gl_lds16(Ab + (size_t)(srow + r * 16) * NC + k0 + scol,
               &As[(w * 32 + r * 16) * 32]);
      gl_lds16(Bb + (size_t)(srow + r * 16) * NC + k0 + scol,
               &Bs[(w * 32 + r * 16) * 32]);
    }
    __syncthreads();
    shortx8 af[4], bfg[4];
#pragma unroll
    for (int t = 0; t < 4; ++t) {
      af[t]  = *(const shortx8*)&As[(wm + t * 16 + fm) * 32 + kg * 8];
      bfg[t] = *(const shortx8*)&Bs[(wn + t * 16 + fm) * 32 + kg * 8];
    }
#pragma unroll
    for (int tm = 0; tm < 4; ++tm)
#pragma unroll
      for (int tn = 0; tn < 4; ++tn)
        acc[tm][tn] = __builtin_amdgcn_mfma_f32_16x16x32_bf16(
            af[tm], bfg[tn], acc[tm][tn], 0, 0, 0);
    __syncthreads();
  }

  float bv[4];
#pragma unroll
  for (int tn = 0; tn < 4; ++tn)
    bv[tn] = bias768[n0 + wn + tn * 16 + fm];

  bf16_t* obase = qkv + ((size_t)b * NN + m0) * 768;
#pragma unroll
  for (int tm = 0; tm < 4; ++tm) {
    int mrow = wm + tm * 16 + kg * 4;
#pragma unroll
    for (int tn = 0; tn < 4; ++tn) {
      int n = n0 + wn + tn * 16 + fm;
#pragma unroll
      for (int r = 0; r < 4; ++r)
        obase[(size_t)(mrow + r) * 768 + n] = f2bf(acc[tm][tn][r] + bv[tn]);
    }
  }
}

// ---------------------------------------------------------------------------
// Kernel 2: focusing feature map, in place on q and k (bf16).
// rscale precomputed per channel -> pure FMA + reductions, memory-bound.
// ---------------------------------------------------------------------------
__global__ __launch_bounds__(256) void k_focus(
    bf16_t* __restrict__ qkv, const float* __restrict__ rscale)
{
  const int lane = threadIdx.x & 63;
  const int w = threadIdx.x >> 6;
  const size_t t = (size_t)blockIdx.x * 4 + w;
  bf16_t* row = qkv + t * 768;
  ushort4 qu = *(ushort4*)(row + lane * 4);
  ushort4 ku = *(ushort4*)(row + 256 + lane * 4);
  float4 s4 = *(const float4*)(rscale + lane * 4);
  float q[4] = {bf2f(qu.x), bf2f(qu.y), bf2f(qu.z), bf2f(qu.w)};
  float k[4] = {bf2f(ku.x), bf2f(ku.y), bf2f(ku.z), bf2f(ku.w)};
  float rs[4] = {s4.x, s4.y, s4.z, s4.w};
  float q3[4], k3[4];
  float sq2 = 0.f, sq6 = 0.f, sk2 = 0.f, sk6 = 0.f;
#pragma unroll
  for (int i = 0; i < 4; ++i) {
    float qi = (fmaxf(q[i], 0.f) + 1e-6f) * rs[i];
    float ki = (fmaxf(k[i], 0.f) + 1e-6f) * rs[i];
    float qc = qi * qi * qi;
    float kc = ki * ki * ki;
    sq2 += qi * qi;  sk2 += ki * ki;
    sq6 += qc * qc;  sk6 += kc * kc;
    q3[i] = qc; k3[i] = kc;
  }
#pragma unroll
  for (int off = 32; off > 0; off >>= 1) {
    sq2 += __shfl_xor(sq2, off);
    sq6 += __shfl_xor(sq6, off);
    sk2 += __shfl_xor(sk2, off);
    sk6 += __shfl_xor(sk6, off);
  }
  float qs = sqrtf(sq2) * rsqrtf(sq6);
  float ks = sqrtf(sk2) * rsqrtf(sk6);
  ushort4 qo, ko;
  qo.x = f2bf(q3[0] * qs); qo.y = f2bf(q3[1] * qs);
  qo.z = f2bf(q3[2] * qs); qo.w = f2bf(q3[3] * qs);
  ko.x = f2bf(k3[0] * ks); ko.y = f2bf(k3[1] * ks);
  ko.z = f2bf(k3[2] * ks); ko.w = f2bf(k3[3] * ks);
  *(ushort4*)(row + lane * 4) = qo;
  *(ushort4*)(row + 256 + lane * 4) = ko;
}

// ---------------------------------------------------------------------------
// Kernel 3: per-head kv_state (32x32) and k-sum, split-K over tokens.
// ---------------------------------------------------------------------------
__global__ __launch_bounds__(256) void k_kvstate(
    const bf16_t* __restrict__ qkv, float* __restrict__ kvsp,
    float* __restrict__ ksump)
{
  const int bh = blockIdx.x;
  const int spl = blockIdx.y;
  const int b = bh >> 3, h = bh & 7;
  __shared__ float ks[64][36];
  __shared__ float vs[64][36];
  const int tid = threadIdx.x;
  const int c = tid >> 3;
  const int d4 = (tid & 7) * 4;
  float acc0 = 0.f, acc1 = 0.f, acc2 = 0.f, acc3 = 0.f, ksacc = 0.f;
  const int t0base = spl * (NN / KSPLIT);
  for (int t0 = t0base; t0 < t0base + NN / KSPLIT; t0 += 64) {
#pragma unroll
    for (int r = 0; r < 2; ++r) {
      int idx = r * 256 + tid;
      int tok = idx >> 3;
      int slot = idx & 7;
      const bf16_t* rowp = qkv + ((size_t)b * NN + t0 + tok) * 768 + 256 + h * HD;
      uint4 u;
      float f[8];
      if (slot < 4) {
        u = *(const uint4*)(rowp + slot * 8);
        bf8_expand(u, f);
#pragma unroll
        for (int e = 0; e < 8; ++e) ks[tok][slot * 8 + e] = f[e];
      } else {
        u = *(const uint4*)(rowp + 256 + (slot - 4) * 8);
        bf8_expand(u, f);
#pragma unroll
        for (int e = 0; e < 8; ++e) vs[tok][(slot - 4) * 8 + e] = f[e];
      }
    }
    __syncthreads();
#pragma unroll 4
    for (int t = 0; t < 64; ++t) {
      float kc = ks[t][c];
      float vv[4];
      *(float4*)vv = *(const float4*)&vs[t][d4];
      acc0 += kc * vv[0]; acc1 += kc * vv[1];
      acc2 += kc * vv[2]; acc3 += kc * vv[3];
      ksacc += kc;
    }
    __syncthreads();
  }
  float o[4] = {acc0, acc1, acc2, acc3};
  *(float4*)(kvsp + ((size_t)spl * BHD + bh) * (HD * HD) + c * HD + d4) = *(float4*)o;
  if (d4 == 0) ksump[((size_t)spl * BHD + bh) * HD + c] = ksacc;
}

// ---------------------------------------------------------------------------
// Kernel 4: combine split-K partials.
// ---------------------------------------------------------------------------
__global__ __launch_bounds__(256) void k_combine(
    const float* __restrict__ kvsp, const float* __restrict__ ksump,
    float* __restrict__ kvs, float* __restrict__ ksum)
{
  int i = blockIdx.x * 256 + threadIdx.x;
  float v = 0.f;
#pragma unroll
  for (int s = 0; s < KSPLIT; ++s) v += kvsp[(size_t)s * BHD * HD * HD + i];
  kvs[i] = v;
  if (i < BHD * HD) {
    float u = 0.f;
#pragma unroll
    for (int s = 0; s < KSPLIT; ++s) u += ksump[(size_t)s * BHD * HD + i];
    ksum[i] = u;
  }
}

// ---------------------------------------------------------------------------
// Kernel 5: attn = (q @ kv_state)*z + depthwise5x5(v) + dwc_b  (bf16 out)
// ---------------------------------------------------------------------------
__global__ __launch_bounds__(256) void k_attnout(
    const bf16_t* __restrict__ qkv, const float* __restrict__ kvs,
    const float* __restrict__ ksum, const float* __restrict__ dwc_w,
    const float* __restrict__ dwc_b, bf16_t* __restrict__ attn)
{
  const int bh = blockIdx.z;
  const int b = bh >> 3, h = bh & 7;
  const int y0 = blockIdx.y * 8, x0 = blockIdx.x * 8;
  __shared__ float qt[64][36];
  __shared__ float vt[32][145];
  __shared__ float zt[64];
  const int tid = threadIdx.x;

  {
    int tok = tid >> 2, slot = tid & 3;
    int ty = tok >> 3, tx = tok & 7;
    int n = (y0 + ty) * 64 + (x0 + tx);
    uint4 u = *(const uint4*)(qkv + ((size_t)b * NN + n) * 768 + h * HD + slot * 8);
    float f[8];
    bf8_expand(u, f);
#pragma unroll
    for (int e = 0; e < 8; ++e) qt[tok][slot * 8 + e] = f[e];
  }
  for (int idx = tid; idx < 576; idx += 256) {
    int ht = idx >> 2, slot = idx & 3;
    int hy = y0 + (ht / 12) - 2;
    int hx = x0 + (ht % 12) - 2;
    float f[8] = {0.f, 0.f, 0.f, 0.f, 0.f, 0.f, 0.f, 0.f};
    if (hy >= 0 && hy < 64 && hx >= 0 && hx < 64) {
      int n = hy * 64 + hx;
      uint4 u = *(const uint4*)(qkv + ((size_t)b * NN + n) * 768 + 512 + h * HD + slot * 8);
      bf8_expand(u, f);
    }
#pragma unroll
    for (int e = 0; e < 8; ++e) vt[slot * 8 + e][ht] = f[e];
  }
  __syncthreads();

  if (tid < 64) {
    float dot = 0.f;
#pragma unroll
    for (int c = 0; c < HD; ++c)
      dot += qt[tid][c] * ksum[(size_t)bh * HD + c];
    zt[tid] = 1.f / (dot + 1e-6f);
  }
  __syncthreads();

  const int d = tid & 31;
  const int tg = tid >> 5;
  float kvc[32];
#pragma unroll
  for (int c = 0; c < 32; ++c)
    kvc[c] = kvs[(size_t)bh * (HD * HD) + c * HD + d];
  float wr[25];
#pragma unroll
  for (int j = 0; j < 25; ++j) wr[j] = dwc_w[d * 25 + j];
  const float bd = dwc_b[d];

#pragma unroll
  for (int tt = 0; tt < 8; ++tt) {
    int t = tg * 8 + tt;
    int ty = t >> 3, tx = t & 7;
    float mv = 0.f;
#pragma unroll
    for (int c = 0; c < 32; ++c) mv += qt[t][c] * kvc[c];
    float acc = mv * zt[t] + bd;
#pragma unroll
    for (int ky = 0; ky < 5; ++ky)
#pragma unroll
      for (int kx = 0; kx < 5; ++kx)
        acc += vt[d][(ty + ky) * 12 + (tx + kx)] * wr[ky * 5 + kx];
    int n = (y0 + ty) * 64 + (x0 + tx);
    attn[((size_t)b * NN + n) * NC + h * HD + d] = f2bf(acc);
  }
}

// ---------------------------------------------------------------------------
// Kernel 6: output projection via bf16 MFMA, fp32 transposed store.
// ---------------------------------------------------------------------------
__global__ __launch_bounds__(256) void k_proj_mfma(
    const bf16_t* __restrict__ attn, const bf16_t* __restrict__ Wpb,
    const float* __restrict__ bp, float* __restrict__ out)
{
  __shared__ bf16_t As[128 * 32];
  __shared__ bf16_t Bs[128 * 32];
  const int tid = threadIdx.x;
  const int lane = tid & 63;
  const int w = tid >> 6;
  const size_t m0 = (size_t)blockIdx.x * 128;
  const int n0 = blockIdx.y * 128;
  const bf16_t* Ab = attn + m0 * NC;
  const bf16_t* Bb = Wpb + (size_t)n0 * NC;

  const int wm = (w & 1) * 64;
  const int wn = (w >> 1) * 64;
  const int srow = w * 32 + (lane >> 2);
  const int scol = (lane & 3) * 8;
  const int fm = lane & 15;
  const int kg = lane >> 4;

  floatx4 acc[4][4];
#pragma unroll
  for (int i = 0; i < 4; ++i)
#pragma unroll
    for (int j = 0; j < 4; ++j) {
      floatx4 z = {0.f, 0.f, 0.f, 0.f};
      acc[i][j] = z;
    }

  for (int k0 = 0; k0 < NC; k0 += 32) {
#pragma unroll
    for (int r = 0; r < 2; ++r) {
      gl_lds16(Ab + (size_t)(srow + r * 16) * NC + k0 + scol,
               &As[(w * 32 + r * 16) * 32]);
      gl_lds16(Bb + (size_t)(srow + r * 16) * NC + k0 + scol,
               &Bs[(w * 32 + r * 16) * 32]);
    }
    __syncthreads();
    shortx8 af[4], bfg[4];
#pragma unroll
    for (int t = 0; t < 4; ++t) {
      af[t]  = *(const shortx8*)&As[(wm + t * 16 + fm) * 32 + kg * 8];
      bfg[t] = *(const shortx8*)&Bs[(wn + t * 16 + fm) * 32 + kg * 8];
    }
#pragma unroll
    for (int tm = 0; tm < 4; ++tm)
#pragma unroll
      for (int tn = 0; tn < 4; ++tn)
        acc[tm][tn] = __builtin_amdgcn_mfma_f32_16x16x32_bf16(
            af[tm], bfg[tn], acc[tm][tn], 0, 0, 0);
    __syncthreads();
  }

  const int b = (int)(m0 >> 12);
  const int t0 = (int)(m0 & 4095);
  float* ob = out + (size_t)b * NC * NN;
#pragma unroll
  for (int tn = 0; tn < 4; ++tn) {
    int j = n0 + wn + tn * 16 + fm;
    float bj = bp[j];
#pragma unroll
    for (int tm = 0; tm < 4; ++tm) {
      int trow = t0 + wm + tm * 16 + kg * 4;
      float4 o;
      o.x = acc[tm][tn][0] + bj;
      o.y = acc[tm][tn][1] + bj;
      o.z = acc[tm][tn][2] + bj;
      o.w = acc[tm][tn][3] + bj;
      *(float4*)(ob + (size_t)j * NN + trow) = o;
    }
  }
}

// ---------------------------------------------------------------------------
extern "C" void kernel_launch(void* const* d_in, const int* in_sizes, int n_in,
                              void* d_out, int out_size, void* d_ws, size_t ws_size,
                              hipStream_t stream)
{
  (void)in_sizes; (void)n_in; (void)out_size; (void)ws_size;
  const float* x    = (const float*)d_in[0];
  const float* Wq   = (const float*)d_in[1];
  const float* bq   = (const float*)d_in[2];
  const float* Wkv  = (const float*)d_in[3];
  const float* bkv  = (const float*)d_in[4];
  const float* Wp   = (const float*)d_in[5];
  const float* bp   = (const float*)d_in[6];
  const float* dwcw = (const float*)d_in[7];
  const float* dwcb = (const float*)d_in[8];
  const float* sp   = (const float*)d_in[9];
  float* out = (float*)d_out;

  char* wsb = (char*)d_ws;
  bf16_t* qkv  = (bf16_t*)wsb;
  bf16_t* attn = (bf16_t*)(wsb + 100663296u);
  bf16_t* xbf  = attn;                                   // alias (disjoint lifetimes)
  float*  kvsp = (float*)(wsb + 100663296u + 33554432u);
  float*  ksump = kvsp + (size_t)KSPLIT * BHD * HD * HD;
  float*  kvs   = ksump + (size_t)KSPLIT * BHD * HD;
  float*  ksum  = kvs + (size_t)BHD * HD * HD;
  bf16_t* Wqkvb = (bf16_t*)(ksum + BHD * HD);
  bf16_t* Wpb   = Wqkvb + 768 * 256;
  float*  bias768 = (float*)(Wpb + 256 * 256);
  float*  rscale  = bias768 + 768;

  k_prepx<<<dim3(64, 4, 16), 256, 0, stream>>>(x, xbf);
  k_prepw<<<1026, 256, 0, stream>>>(Wq, Wkv, Wp, bq, bkv, sp, Wqkvb, Wpb, bias768, rscale);
  k_qkv_mfma<<<dim3(32, 6, 16), 256, 0, stream>>>(xbf, Wqkvb, bias768, qkv);
  k_focus<<<16384, 256, 0, stream>>>(qkv, rscale);
  k_kvstate<<<dim3(BHD, KSPLIT), 256, 0, stream>>>(qkv, kvsp, ksump);
  k_combine<<<512, 256, 0, stream>>>(kvsp, ksump, kvs, ksum);
  k_attnout<<<dim3(8, 8, BHD), 256, 0, stream>>>(qkv, kvs, ksum, dwcw, dwcb, attn);
  k_proj_mfma<<<dim3(512, 2), 256, 0, stream>>>(attn, Wpb, bp, out);
}

// Round 5
// 310.805 us; speedup vs baseline: 2.1972x; 1.0858x over previous
//
#include <hip/hip_runtime.h>
#include <math.h>

#define NB 16
#define NC 256
#define NN 4096
#define HD 32
#define BHD 128   // NB*NHD
#define KSPLIT 4

typedef unsigned short bf16_t;
typedef __attribute__((ext_vector_type(4))) float floatx4;
typedef __attribute__((ext_vector_type(8))) short shortx8;

__device__ __forceinline__ float bf2f(unsigned int u16) {
  return __uint_as_float(u16 << 16);
}
__device__ __forceinline__ bf16_t f2bf(float f) {
  unsigned int u = __float_as_uint(f);
  return (bf16_t)((u + 0x7FFFu + ((u >> 16) & 1u)) >> 16);
}
__device__ __forceinline__ void bf8_expand(uint4 u, float* f) {
  f[0] = bf2f(u.x & 0xffffu); f[1] = bf2f(u.x >> 16);
  f[2] = bf2f(u.y & 0xffffu); f[3] = bf2f(u.y >> 16);
  f[4] = bf2f(u.z & 0xffffu); f[5] = bf2f(u.z >> 16);
  f[6] = bf2f(u.w & 0xffffu); f[7] = bf2f(u.w >> 16);
}
__device__ __forceinline__ float softplusf(float x) {
  return fmaxf(x, 0.0f) + log1pf(expf(-fabsf(x)));
}

// async global->LDS, 16B per lane; lds base must be wave-uniform
__device__ __forceinline__ void gl_lds16(const void* g, void* l) {
  __builtin_amdgcn_global_load_lds(
      (const __attribute__((address_space(1))) unsigned int*)g,
      (__attribute__((address_space(3))) unsigned int*)l, 16, 0, 0);
}

// ---------------------------------------------------------------------------
// prep: x [b][c][n] fp32 -> xbf [b][n][c] bf16 (transpose + cast)
// ---------------------------------------------------------------------------
__global__ __launch_bounds__(256) void k_prepx(
    const float* __restrict__ x, bf16_t* __restrict__ xbf)
{
  __shared__ float T[64][68];
  const int tid = threadIdx.x;
  const int n0 = blockIdx.x * 64, c0 = blockIdx.y * 64, b = blockIdx.z;
  const float* xb = x + (size_t)b * NC * NN;
#pragma unroll
  for (int it = 0; it < 4; ++it) {
    int c = it * 16 + (tid >> 4);
    int n4 = (tid & 15) * 4;
    float4 v = *(const float4*)(xb + (size_t)(c0 + c) * NN + n0 + n4);
    T[c][n4 + 0] = v.x; T[c][n4 + 1] = v.y;
    T[c][n4 + 2] = v.z; T[c][n4 + 3] = v.w;
  }
  __syncthreads();
  bf16_t* ob = xbf + (size_t)b * NN * NC;
#pragma unroll
  for (int it = 0; it < 2; ++it) {
    int n = it * 32 + (tid >> 3);
    int ch = (tid & 7) * 8;
    unsigned short e[8];
#pragma unroll
    for (int j = 0; j < 8; ++j) e[j] = f2bf(T[ch + j][n]);
    uint4 u;
    u.x = e[0] | ((unsigned)e[1] << 16); u.y = e[2] | ((unsigned)e[3] << 16);
    u.z = e[4] | ((unsigned)e[5] << 16); u.w = e[6] | ((unsigned)e[7] << 16);
    *(uint4*)(ob + (size_t)(n0 + n) * NC + c0 + ch) = u;
  }
}

// ---------------------------------------------------------------------------
// prep: pack weights to bf16, biases, and rscale[c] = 1/softplus(scale[c])
// ---------------------------------------------------------------------------
__global__ __launch_bounds__(256) void k_prepw(
    const float* __restrict__ Wq, const float* __restrict__ Wkv,
    const float* __restrict__ Wp, const float* __restrict__ bq,
    const float* __restrict__ bkv, const float* __restrict__ sp,
    bf16_t* __restrict__ Wqkvb, bf16_t* __restrict__ Wpb,
    float* __restrict__ bias768, float* __restrict__ rscale)
{
  const int blk = blockIdx.x;
  const int tid = threadIdx.x;
  if (blk < 768) {
    const float* src = (blk < 256) ? (Wq + (size_t)blk * NC)
                                   : (Wkv + (size_t)(blk - 256) * NC);
    Wqkvb[(size_t)blk * NC + tid] = f2bf(src[tid]);
  } else if (blk < 1024) {
    int j = blk - 768;
    Wpb[(size_t)j * NC + tid] = f2bf(Wp[(size_t)j * NC + tid]);
  } else if (blk == 1024) {
    for (int i = tid; i < 768; i += 256)
      bias768[i] = (i < 256) ? bq[i] : bkv[i - 256];
  } else {
    rscale[tid] = 1.0f / softplusf(sp[tid]);
  }
}

// ---------------------------------------------------------------------------
// Kernel 1: qkv projection via bf16 MFMA. 128x128 tile, BK=32.
// ---------------------------------------------------------------------------
__global__ __launch_bounds__(256) void k_qkv_mfma(
    const bf16_t* __restrict__ xbf, const bf16_t* __restrict__ Wqkvb,
    const float* __restrict__ bias768, bf16_t* __restrict__ qkv)
{
  __shared__ bf16_t As[128 * 32];
  __shared__ bf16_t Bs[128 * 32];
  const int tid = threadIdx.x;
  const int lane = tid & 63;
  const int w = tid >> 6;
  const int b = blockIdx.z;
  const int m0 = blockIdx.x * 128;
  const int n0 = blockIdx.y * 128;
  const bf16_t* Ab = xbf + ((size_t)b * NN + m0) * NC;
  const bf16_t* Bb = Wqkvb + (size_t)n0 * NC;

  const int wm = (w & 1) * 64;
  const int wn = (w >> 1) * 64;
  const int srow = w * 32 + (lane >> 2);
  const int scol = (lane & 3) * 8;
  const int fm = lane & 15;
  const int kg = lane >> 4;

  floatx4 acc[4][4];
#pragma unroll
  for (int i = 0; i < 4; ++i)
#pragma unroll
    for (int j = 0; j < 4; ++j) {
      floatx4 z = {0.f, 0.f, 0.f, 0.f};
      acc[i][j] = z;
    }

  for (int k0 = 0; k0 < NC; k0 += 32) {
#pragma unroll
    for (int r = 0; r < 2; ++r) {
      gl_lds16(Ab + (size_t)(srow + r * 16) * NC + k0 + scol,
               &As[(w * 32 + r * 16) * 32]);
      gl_lds16(Bb + (size_t)(srow + r * 16) * NC + k0 + scol,
               &Bs[(w * 32 + r * 16) * 32]);
    }
    __syncthreads();
    shortx8 af[4], bfg[4];
#pragma unroll
    for (int t = 0; t < 4; ++t) {
      af[t]  = *(const shortx8*)&As[(wm + t * 16 + fm) * 32 + kg * 8];
      bfg[t] = *(const shortx8*)&Bs[(wn + t * 16 + fm) * 32 + kg * 8];
    }
#pragma unroll
    for (int tm = 0; tm < 4; ++tm)
#pragma unroll
      for (int tn = 0; tn < 4; ++tn)
        acc[tm][tn] = __builtin_amdgcn_mfma_f32_16x16x32_bf16(
            af[tm], bfg[tn], acc[tm][tn], 0, 0, 0);
    __syncthreads();
  }

  float bv[4];
#pragma unroll
  for (int tn = 0; tn < 4; ++tn)
    bv[tn] = bias768[n0 + wn + tn * 16 + fm];

  bf16_t* obase = qkv + ((size_t)b * NN + m0) * 768;
#pragma unroll
  for (int tm = 0; tm < 4; ++tm) {
    int mrow = wm + tm * 16 + kg * 4;
#pragma unroll
    for (int tn = 0; tn < 4; ++tn) {
      int n = n0 + wn + tn * 16 + fm;
#pragma unroll
      for (int r = 0; r < 4; ++r)
        obase[(size_t)(mrow + r) * 768 + n] = f2bf(acc[tm][tn][r] + bv[tn]);
    }
  }
}

// ---------------------------------------------------------------------------
// Kernel 2: focusing feature map, in place on q and k (bf16).
// ---------------------------------------------------------------------------
__global__ __launch_bounds__(256) void k_focus(
    bf16_t* __restrict__ qkv, const float* __restrict__ rscale)
{
  const int lane = threadIdx.x & 63;
  const int w = threadIdx.x >> 6;
  const size_t t = (size_t)blockIdx.x * 4 + w;
  bf16_t* row = qkv + t * 768;
  ushort4 qu = *(ushort4*)(row + lane * 4);
  ushort4 ku = *(ushort4*)(row + 256 + lane * 4);
  float4 s4 = *(const float4*)(rscale + lane * 4);
  float q[4] = {bf2f(qu.x), bf2f(qu.y), bf2f(qu.z), bf2f(qu.w)};
  float k[4] = {bf2f(ku.x), bf2f(ku.y), bf2f(ku.z), bf2f(ku.w)};
  float rs[4] = {s4.x, s4.y, s4.z, s4.w};
  float q3[4], k3[4];
  float sq2 = 0.f, sq6 = 0.f, sk2 = 0.f, sk6 = 0.f;
#pragma unroll
  for (int i = 0; i < 4; ++i) {
    float qi = (fmaxf(q[i], 0.f) + 1e-6f) * rs[i];
    float ki = (fmaxf(k[i], 0.f) + 1e-6f) * rs[i];
    float qc = qi * qi * qi;
    float kc = ki * ki * ki;
    sq2 += qi * qi;  sk2 += ki * ki;
    sq6 += qc * qc;  sk6 += kc * kc;
    q3[i] = qc; k3[i] = kc;
  }
#pragma unroll
  for (int off = 32; off > 0; off >>= 1) {
    sq2 += __shfl_xor(sq2, off);
    sq6 += __shfl_xor(sq6, off);
    sk2 += __shfl_xor(sk2, off);
    sk6 += __shfl_xor(sk6, off);
  }
  float qs = sqrtf(sq2) * rsqrtf(sq6);
  float ks = sqrtf(sk2) * rsqrtf(sk6);
  ushort4 qo, ko;
  qo.x = f2bf(q3[0] * qs); qo.y = f2bf(q3[1] * qs);
  qo.z = f2bf(q3[2] * qs); qo.w = f2bf(q3[3] * qs);
  ko.x = f2bf(k3[0] * ks); ko.y = f2bf(k3[1] * ks);
  ko.z = f2bf(k3[2] * ks); ko.w = f2bf(k3[3] * ks);
  *(ushort4*)(row + lane * 4) = qo;
  *(ushort4*)(row + 256 + lane * 4) = ko;
}

// ---------------------------------------------------------------------------
// Kernel 3: per-head kv_state (32x32) and k-sum, split-K over tokens.
// ---------------------------------------------------------------------------
__global__ __launch_bounds__(256) void k_kvstate(
    const bf16_t* __restrict__ qkv, float* __restrict__ kvsp,
    float* __restrict__ ksump)
{
  const int bh = blockIdx.x;
  const int spl = blockIdx.y;
  const int b = bh >> 3, h = bh & 7;
  __shared__ float ks[64][36];
  __shared__ float vs[64][36];
  const int tid = threadIdx.x;
  const int c = tid >> 3;
  const int d4 = (tid & 7) * 4;
  float acc0 = 0.f, acc1 = 0.f, acc2 = 0.f, acc3 = 0.f, ksacc = 0.f;
  const int t0base = spl * (NN / KSPLIT);
  for (int t0 = t0base; t0 < t0base + NN / KSPLIT; t0 += 64) {
#pragma unroll
    for (int r = 0; r < 2; ++r) {
      int idx = r * 256 + tid;
      int tok = idx >> 3;
      int slot = idx & 7;
      const bf16_t* rowp = qkv + ((size_t)b * NN + t0 + tok) * 768 + 256 + h * HD;
      uint4 u;
      float f[8];
      if (slot < 4) {
        u = *(const uint4*)(rowp + slot * 8);
        bf8_expand(u, f);
#pragma unroll
        for (int e = 0; e < 8; ++e) ks[tok][slot * 8 + e] = f[e];
      } else {
        u = *(const uint4*)(rowp + 256 + (slot - 4) * 8);
        bf8_expand(u, f);
#pragma unroll
        for (int e = 0; e < 8; ++e) vs[tok][(slot - 4) * 8 + e] = f[e];
      }
    }
    __syncthreads();
#pragma unroll 4
    for (int t = 0; t < 64; ++t) {
      float kc = ks[t][c];
      float vv[4];
      *(float4*)vv = *(const float4*)&vs[t][d4];
      acc0 += kc * vv[0]; acc1 += kc * vv[1];
      acc2 += kc * vv[2]; acc3 += kc * vv[3];
      ksacc += kc;
    }
    __syncthreads();
  }
  float o[4] = {acc0, acc1, acc2, acc3};
  *(float4*)(kvsp + ((size_t)spl * BHD + bh) * (HD * HD) + c * HD + d4) = *(float4*)o;
  if (d4 == 0) ksump[((size_t)spl * BHD + bh) * HD + c] = ksacc;
}

// ---------------------------------------------------------------------------
// Kernel 4: combine split-K partials -> kvT bf16 [bh][d][c], ksumb bf16 [bh][c]
// ---------------------------------------------------------------------------
__global__ __launch_bounds__(256) void k_combine(
    const float* __restrict__ kvsp, const float* __restrict__ ksump,
    bf16_t* __restrict__ kvTb, bf16_t* __restrict__ ksumb)
{
  const int bh = blockIdx.x;
  const int tid = threadIdx.x;
  const int c = tid >> 3;
  const int d4 = (tid & 7) * 4;
  float v[4] = {0.f, 0.f, 0.f, 0.f};
#pragma unroll
  for (int s = 0; s < KSPLIT; ++s) {
    const float* p = kvsp + ((size_t)s * BHD + bh) * (HD * HD) + c * HD + d4;
#pragma unroll
    for (int e = 0; e < 4; ++e) v[e] += p[e];
  }
#pragma unroll
  for (int e = 0; e < 4; ++e)
    kvTb[(size_t)bh * (HD * HD) + (d4 + e) * HD + c] = f2bf(v[e]);
  if (d4 == 0) {
    float u = 0.f;
#pragma unroll
    for (int s = 0; s < KSPLIT; ++s) u += ksump[((size_t)s * BHD + bh) * HD + c];
    ksumb[(size_t)bh * HD + c] = f2bf(u);
  }
}

// ---------------------------------------------------------------------------
// Kernel 5: attn = (q @ kv_state)*z + depthwise5x5(v) + dwc_b  (bf16 out)
// Matvec + z via MFMA (A=q direct from global, B=kvT / ksumb);
// conv via column-major LDS v-tile + register sliding window.
// Block = (strip of 4 rows x 64 cols, one bh) = 256 tokens. grid (16, 128).
// ---------------------------------------------------------------------------
#define VT_STRIDE 548   // bf16 per d-plane (68 cols * 8 ry = 544, pad->548; 274 words, mod32=18 -> 2-way)
__global__ __launch_bounds__(256) void k_attnout(
    const bf16_t* __restrict__ qkv, const bf16_t* __restrict__ kvTb,
    const bf16_t* __restrict__ ksumb, const float* __restrict__ dwc_w,
    const float* __restrict__ dwc_b, bf16_t* __restrict__ attn)
{
  __shared__ bf16_t vt[32 * VT_STRIDE];   // [d][col(68)][ry(8)]
  __shared__ bf16_t mvz[256 * 32];        // [token][d]
  const int tid = threadIdx.x;
  const int lane = tid & 63;
  const int w = tid >> 6;
  const int s = blockIdx.x;        // strip: rows 4s..4s+3
  const int bh = blockIdx.y;
  const int b = bh >> 3, h = bh & 7;

  // ---- stage v halo: rows y=4s-2+ry (ry 0..7), cols 0..63, 32 ch ----
#pragma unroll
  for (int it = 0; it < 8; ++it) {
    int idx = it * 256 + tid;          // 0..2047 = ry(8) x col(64) x slot(4)
    int ry = idx >> 8;
    int col = (idx >> 2) & 63;
    int slot = idx & 3;                // 8 ch each
    int y = s * 4 - 2 + ry;
    uint4 u = make_uint4(0u, 0u, 0u, 0u);
    if (y >= 0 && y < 64)
      u = *(const uint4*)(qkv + ((size_t)b * NN + y * 64 + col) * 768 + 512 + h * HD + slot * 8);
    unsigned short e[8];
    e[0] = (unsigned short)(u.x & 0xffffu); e[1] = (unsigned short)(u.x >> 16);
    e[2] = (unsigned short)(u.y & 0xffffu); e[3] = (unsigned short)(u.y >> 16);
    e[4] = (unsigned short)(u.z & 0xffffu); e[5] = (unsigned short)(u.z >> 16);
    e[6] = (unsigned short)(u.w & 0xffffu); e[7] = (unsigned short)(u.w >> 16);
#pragma unroll
    for (int j = 0; j < 8; ++j)
      vt[(slot * 8 + j) * VT_STRIDE + (col + 2) * 8 + ry] = e[j];
  }
  // zero halo cols cc in {0,1,66,67}: 32 d x 4 cc x 8 ry = 1024
#pragma unroll
  for (int e = 0; e < 4; ++e) {
    int idx = tid * 4 + e;             // 0..1023
    int d = idx >> 5;
    int rem = idx & 31;
    int cc4 = rem >> 3;                // 0..3
    int ry = rem & 7;
    int cc = (cc4 < 2) ? cc4 : (64 + cc4);
    vt[d * VT_STRIDE + cc * 8 + ry] = 0;
  }

  // ---- MFMA matvec: 16 m-tiles of 16 tokens; wave w handles 4 tiles ----
  const int fm = lane & 15;
  const int kg = lane >> 4;
  shortx8 b0 = *(const shortx8*)(kvTb + (size_t)bh * 1024 + fm * HD + kg * 8);
  shortx8 b1 = *(const shortx8*)(kvTb + (size_t)bh * 1024 + (16 + fm) * HD + kg * 8);
  shortx8 b2 = {0, 0, 0, 0, 0, 0, 0, 0};
  if (fm == 0) b2 = *(const shortx8*)(ksumb + (size_t)bh * HD + kg * 8);
  floatx4 zf = {0.f, 0.f, 0.f, 0.f};
#pragma unroll
  for (int q = 0; q < 4; ++q) {
    int mt = w * 4 + q;
    int tok = s * 256 + mt * 16 + fm;  // n within b
    shortx8 a = *(const shortx8*)(qkv + ((size_t)b * NN + tok) * 768 + h * HD + kg * 8);
    floatx4 d0 = __builtin_amdgcn_mfma_f32_16x16x32_bf16(a, b0, zf, 0, 0, 0);
    floatx4 d1 = __builtin_amdgcn_mfma_f32_16x16x32_bf16(a, b1, zf, 0, 0, 0);
    floatx4 d2 = __builtin_amdgcn_mfma_f32_16x16x32_bf16(a, b2, zf, 0, 0, 0);
#pragma unroll
    for (int r = 0; r < 4; ++r) {
      float qk = __shfl(d2[r], lane & 48);
      float z = 1.0f / (qk + 1e-6f);
      int tl = mt * 16 + kg * 4 + r;   // local token 0..255
      mvz[tl * 32 + fm] = f2bf(d0[r] * z);
      mvz[tl * 32 + 16 + fm] = f2bf(d1[r] * z);
    }
  }
  __syncthreads();

  // ---- conv + combine: thread = (d, xg); 8 x-cols x 4 ty ----
  const int d = tid & 31;
  const int xg = tid >> 5;
  const int x0c = xg * 8;
  float wr[25];
#pragma unroll
  for (int j = 0; j < 25; ++j) wr[j] = dwc_w[d * 25 + j];
  const float bd = dwc_b[d];
  const bf16_t* vd = vt + d * VT_STRIDE;

  float win[5][8];
#define LOADCOL(dst, cc) do {                                   \
    const bf16_t* _p = vd + (cc) * 8;                           \
    uint2 _u0 = *(const uint2*)_p;                              \
    uint2 _u1 = *(const uint2*)(_p + 4);                        \
    (dst)[0] = bf2f(_u0.x & 0xffffu); (dst)[1] = bf2f(_u0.x >> 16); \
    (dst)[2] = bf2f(_u0.y & 0xffffu); (dst)[3] = bf2f(_u0.y >> 16); \
    (dst)[4] = bf2f(_u1.x & 0xffffu); (dst)[5] = bf2f(_u1.x >> 16); \
    (dst)[6] = bf2f(_u1.y & 0xffffu); (dst)[7] = bf2f(_u1.y >> 16); \
  } while (0)

#pragma unroll
  for (int p = 0; p < 4; ++p) LOADCOL(win[p], x0c + p);

  bf16_t* arow = attn + ((size_t)b * NN + s * 256) * NC + h * HD + d;
#pragma unroll
  for (int i = 0; i < 8; ++i) {
    int x = x0c + i;
    LOADCOL(win[4], x + 4);
#pragma unroll
    for (int ty = 0; ty < 4; ++ty) {
      float acc = bd;
#pragma unroll
      for (int ky = 0; ky < 5; ++ky)
#pragma unroll
        for (int kx = 0; kx < 5; ++kx)
          acc += wr[ky * 5 + kx] * win[kx][ty + ky];
      int tl = ty * 64 + x;
      acc += bf2f(mvz[tl * 32 + d]);
      arow[(size_t)tl * NC] = f2bf(acc);
    }
    // rotate window (compile-time renamed under full unroll)
#pragma unroll
    for (int c2 = 0; c2 < 4; ++c2)
#pragma unroll
      for (int r2 = 0; r2 < 8; ++r2) win[c2][r2] = win[c2 + 1][r2];
  }
#undef LOADCOL
}

// ---------------------------------------------------------------------------
// Kernel 6: output projection via bf16 MFMA, fp32 transposed store.
// ---------------------------------------------------------------------------
__global__ __launch_bounds__(256) void k_proj_mfma(
    const bf16_t* __restrict__ attn, const bf16_t* __restrict__ Wpb,
    const float* __restrict__ bp, float* __restrict__ out)
{
  __shared__ bf16_t As[128 * 32];
  __shared__ bf16_t Bs[128 * 32];
  const int tid = threadIdx.x;
  const int lane = tid & 63;
  const int w = tid >> 6;
  const size_t m0 = (size_t)blockIdx.x * 128;
  const int n0 = blockIdx.y * 128;
  const bf16_t* Ab = attn + m0 * NC;
  const bf16_t* Bb = Wpb + (size_t)n0 * NC;

  const int wm = (w & 1) * 64;
  const int wn = (w >> 1) * 64;
  const int srow = w * 32 + (lane >> 2);
  const int scol = (lane & 3) * 8;
  const int fm = lane & 15;
  const int kg = lane >> 4;

  floatx4 acc[4][4];
#pragma unroll
  for (int i = 0; i < 4; ++i)
#pragma unroll
    for (int j = 0; j < 4; ++j) {
      floatx4 z = {0.f, 0.f, 0.f, 0.f};
      acc[i][j] = z;
    }

  for (int k0 = 0; k0 < NC; k0 += 32) {
#pragma unroll
    for (int r = 0; r < 2; ++r) {
      gl_lds16(Ab + (size_t)(srow + r * 16) * NC + k0 + scol,
               &As[(w * 32 + r * 16) * 32]);
      gl_lds16(Bb + (size_t)(srow + r * 16) * NC + k0 + scol,
               &Bs[(w * 32 + r * 16) * 32]);
    }
    __syncthreads();
    shortx8 af[4], bfg[4];
#pragma unroll
    for (int t = 0; t < 4; ++t) {
      af[t]  = *(const shortx8*)&As[(wm + t * 16 + fm) * 32 + kg * 8];
      bfg[t] = *(const shortx8*)&Bs[(wn + t * 16 + fm) * 32 + kg * 8];
    }
#pragma unroll
    for (int tm = 0; tm < 4; ++tm)
#pragma unroll
      for (int tn = 0; tn < 4; ++tn)
        acc[tm][tn] = __builtin_amdgcn_mfma_f32_16x16x32_bf16(
            af[tm], bfg[tn], acc[tm][tn], 0, 0, 0);
    __syncthreads();
  }

  const int b = (int)(m0 >> 12);
  const int t0 = (int)(m0 & 4095);
  float* ob = out + (size_t)b * NC * NN;
#pragma unroll
  for (int tn = 0; tn < 4; ++tn) {
    int j = n0 + wn + tn * 16 + fm;
    float bj = bp[j];
#pragma unroll
    for (int tm = 0; tm < 4; ++tm) {
      int trow = t0 + wm + tm * 16 + kg * 4;
      float4 o;
      o.x = acc[tm][tn][0] + bj;
      o.y = acc[tm][tn][1] + bj;
      o.z = acc[tm][tn][2] + bj;
      o.w = acc[tm][tn][3] + bj;
      *(float4*)(ob + (size_t)j * NN + trow) = o;
    }
  }
}

// ---------------------------------------------------------------------------
extern "C" void kernel_launch(void* const* d_in, const int* in_sizes, int n_in,
                              void* d_out, int out_size, void* d_ws, size_t ws_size,
                              hipStream_t stream)
{
  (void)in_sizes; (void)n_in; (void)out_size; (void)ws_size;
  const float* x    = (const float*)d_in[0];
  const float* Wq   = (const float*)d_in[1];
  const float* bq   = (const float*)d_in[2];
  const float* Wkv  = (const float*)d_in[3];
  const float* bkv  = (const float*)d_in[4];
  const float* Wp   = (const float*)d_in[5];
  const float* bp   = (const float*)d_in[6];
  const float* dwcw = (const float*)d_in[7];
  const float* dwcb = (const float*)d_in[8];
  const float* sp   = (const float*)d_in[9];
  float* out = (float*)d_out;

  char* wsb = (char*)d_ws;
  bf16_t* qkv  = (bf16_t*)wsb;                            // 100,663,296 B
  bf16_t* attn = (bf16_t*)(wsb + 100663296u);             // 33,554,432 B
  bf16_t* xbf  = attn;                                    // alias (disjoint lifetimes)
  float*  kvsp = (float*)(wsb + 100663296u + 33554432u);  // 2,097,152 B
  float*  ksump = kvsp + (size_t)KSPLIT * BHD * HD * HD;  // 65,536 B
  bf16_t* kvTb  = (bf16_t*)(ksump + (size_t)KSPLIT * BHD * HD);  // 262,144 B
  bf16_t* ksumb = kvTb + (size_t)BHD * HD * HD;           // 8,192 B
  bf16_t* Wqkvb = ksumb + (size_t)BHD * HD;               // 393,216 B
  bf16_t* Wpb   = Wqkvb + 768 * 256;                      // 131,072 B
  float*  bias768 = (float*)(Wpb + 256 * 256);
  float*  rscale  = bias768 + 768;

  k_prepx<<<dim3(64, 4, 16), 256, 0, stream>>>(x, xbf);
  k_prepw<<<1026, 256, 0, stream>>>(Wq, Wkv, Wp, bq, bkv, sp, Wqkvb, Wpb, bias768, rscale);
  k_qkv_mfma<<<dim3(32, 6, 16), 256, 0, stream>>>(xbf, Wqkvb, bias768, qkv);
  k_focus<<<16384, 256, 0, stream>>>(qkv, rscale);
  k_kvstate<<<dim3(BHD, KSPLIT), 256, 0, stream>>>(qkv, kvsp, ksump);
  k_combine<<<BHD, 256, 0, stream>>>(kvsp, ksump, kvTb, ksumb);
  k_attnout<<<dim3(16, BHD), 256, 0, stream>>>(qkv, kvTb, ksumb, dwcw, dwcb, attn);
  k_proj_mfma<<<dim3(512, 2), 256, 0, stream>>>(attn, Wpb, bp, out);
}